// Round 2
// baseline (1053.539 us; speedup 1.0000x reference)
//
#include <hip/hip_runtime.h>

#define HDIM  64
#define INDIM 7
#define QDIM  3
#define TDEC  288
#define SEQ   512
#define NB    4        // batches per block
#define CHUNK 32       // x timesteps staged per LDS chunk

__device__ __forceinline__ float fast_rcp(float x) {
    return __builtin_amdgcn_rcpf(x);   // v_rcp_f32, ~1 ulp
}
__device__ __forceinline__ float sigm(float x) {
    return fast_rcp(1.0f + __expf(-x));
}
__device__ __forceinline__ float tanh_f(float x) {
    float xx = fminf(fmaxf(x, -15.0f), 15.0f);
    float e = __expf(2.0f * xx);
    return (e - 1.0f) * fast_rcp(e + 1.0f);
}

// One block = NB batch elements, full encoder (512 steps) + decoder (288 steps).
// GEMM phase: thread (wave=gate g, lane=unit j) owns W_hh row g*64+j in VGPRs
// (pinned via asm so the compiler cannot rematerialize the loads inside the
// 512-step loop); h read from LDS via same-address broadcast (conflict-free).
// Activation phase: thread -> (batch=wave, unit=lane), c stays in a register.
__global__ __launch_bounds__(256, 2)
void enc_dec_kernel(const float* __restrict__ x,
                    const float* __restrict__ eWih, const float* __restrict__ eWhh,
                    const float* __restrict__ ebih, const float* __restrict__ ebhh,
                    const float* __restrict__ dWih, const float* __restrict__ dWhh,
                    const float* __restrict__ dbih, const float* __restrict__ dbhh,
                    const float* __restrict__ oW,   const float* __restrict__ obv,
                    float* __restrict__ out)
{
    __shared__ float lds_h[NB][HDIM];
    __shared__ float lds_g[NB][4 * HDIM];
    __shared__ float lds_x[2][NB][CHUNK][8];   // padded 7->8, pad lane zeroed

    const int tid  = threadIdx.x;
    const int lane = tid & 63;
    const int wid  = tid >> 6;
    const int b0   = blockIdx.x * NB;

    const int row = wid * HDIM + lane;   // gate-matrix row this thread owns

    // ---- encoder weights into registers, PINNED (no remat possible) ----
    float4 whh[16];
#pragma unroll
    for (int m4 = 0; m4 < 16; ++m4)
        whh[m4] = *reinterpret_cast<const float4*>(&eWhh[row * HDIM + m4 * 4]);
#pragma unroll
    for (int m4 = 0; m4 < 16; ++m4)
        asm volatile("" : "+v"(whh[m4].x), "+v"(whh[m4].y), "+v"(whh[m4].z), "+v"(whh[m4].w));

    float wih[8];
#pragma unroll
    for (int k = 0; k < 7; ++k) wih[k] = eWih[row * INDIM + k];
    wih[7] = 0.0f;
#pragma unroll
    for (int k = 0; k < 7; ++k) asm volatile("" : "+v"(wih[k]));

    float bias = ebih[row] + ebhh[row];
    asm volatile("" : "+v"(bias));

    // ---- init state ----
    lds_h[wid][lane] = 0.0f;   // 256 threads cover NB*HDIM exactly
    float c_reg = 0.0f;        // c for (batch=wid, unit=lane)

    // ---- load x chunk 0 ----
    for (int i = tid; i < NB * CHUNK * 8; i += 256) {
        int b = i >> 8;          // CHUNK*8 == 256
        int r = i & 255;
        int s = r >> 3;
        int k = r & 7;
        float v = 0.0f;
        if (k < 7) v = x[((size_t)(b0 + b) * SEQ + s) * INDIM + k];
        lds_x[0][b][s][k] = v;
    }
    __syncthreads();

    // ================= encoder: 512 serial steps =================
    for (int s = 0; s < SEQ; ++s) {
        const int cs  = s & (CHUNK - 1);
        const int buf = (s >> 5) & 1;

        // ---- GEMM phase: gates[b][row] for NB batches ----
        float acc[NB];
#pragma unroll
        for (int b = 0; b < NB; ++b) acc[b] = bias;

#pragma unroll
        for (int b = 0; b < NB; ++b) {
            const float4 xlo = *reinterpret_cast<const float4*>(&lds_x[buf][b][cs][0]);
            const float4 xhi = *reinterpret_cast<const float4*>(&lds_x[buf][b][cs][4]);
            acc[b] += xlo.x * wih[0] + xlo.y * wih[1] + xlo.z * wih[2] + xlo.w * wih[3]
                    + xhi.x * wih[4] + xhi.y * wih[5] + xhi.z * wih[6];
        }
#pragma unroll
        for (int m4 = 0; m4 < 16; ++m4) {
            const float4 w = whh[m4];
            float4 hv[NB];
#pragma unroll
            for (int b = 0; b < NB; ++b)
                hv[b] = *reinterpret_cast<const float4*>(&lds_h[b][m4 * 4]);
            // component-major: dependent FMAs to the same acc are NB apart
#pragma unroll
            for (int b = 0; b < NB; ++b) acc[b] = fmaf(hv[b].x, w.x, acc[b]);
#pragma unroll
            for (int b = 0; b < NB; ++b) acc[b] = fmaf(hv[b].y, w.y, acc[b]);
#pragma unroll
            for (int b = 0; b < NB; ++b) acc[b] = fmaf(hv[b].z, w.z, acc[b]);
#pragma unroll
            for (int b = 0; b < NB; ++b) acc[b] = fmaf(hv[b].w, w.w, acc[b]);
        }
#pragma unroll
        for (int b = 0; b < NB; ++b) lds_g[b][row] = acc[b];
        __syncthreads();

        // ---- activation phase: thread -> (batch=wid, unit=lane) ----
        {
            const int b = wid, j = lane;
            float ig = sigm(lds_g[b][j]);
            float fg = sigm(lds_g[b][HDIM + j]);
            float gg = tanh_f(lds_g[b][2 * HDIM + j]);
            float og = sigm(lds_g[b][3 * HDIM + j]);
            c_reg = fg * c_reg + ig * gg;
            lds_h[b][j] = og * tanh_f(c_reg);
        }

        // ---- prefetch next x chunk (a full chunk of slack to hide HBM) ----
        if (cs == 0 && s + CHUNK < SEQ) {
            const int nbuf = buf ^ 1;
            const int s0n  = s + CHUNK;
            for (int i = tid; i < NB * CHUNK * 8; i += 256) {
                int b = i >> 8;
                int r = i & 255;
                int ss = r >> 3;
                int k = r & 7;
                float v = 0.0f;
                if (k < 7) v = x[((size_t)(b0 + b) * SEQ + (s0n + ss)) * INDIM + k];
                lds_x[nbuf][b][ss][k] = v;
            }
        }
        __syncthreads();
    }
    // lds_h = h_enc; c_reg (thread (wid,lane)) = c_enc[b][j]

    // ====== decoder gbase = b + h_enc @ dW_hh.T  (constant over all T steps) ======
    {
        float4 dwhh[16];
#pragma unroll
        for (int m4 = 0; m4 < 16; ++m4)
            dwhh[m4] = *reinterpret_cast<const float4*>(&dWhh[row * HDIM + m4 * 4]);
        const float dbias = dbih[row] + dbhh[row];

        float acc[NB];
#pragma unroll
        for (int b = 0; b < NB; ++b) acc[b] = dbias;
#pragma unroll
        for (int m4 = 0; m4 < 16; ++m4) {
            const float4 w = dwhh[m4];
            float4 hv[NB];
#pragma unroll
            for (int b = 0; b < NB; ++b)
                hv[b] = *reinterpret_cast<const float4*>(&lds_h[b][m4 * 4]);
#pragma unroll
            for (int b = 0; b < NB; ++b) acc[b] = fmaf(hv[b].x, w.x, acc[b]);
#pragma unroll
            for (int b = 0; b < NB; ++b) acc[b] = fmaf(hv[b].y, w.y, acc[b]);
#pragma unroll
            for (int b = 0; b < NB; ++b) acc[b] = fmaf(hv[b].z, w.z, acc[b]);
#pragma unroll
            for (int b = 0; b < NB; ++b) acc[b] = fmaf(hv[b].w, w.w, acc[b]);
        }
#pragma unroll
        for (int b = 0; b < NB; ++b) lds_g[b][row] = acc[b];
    }
    __syncthreads();

    // ================= decoder: wave = one batch, lane = unit =================
    {
        const int b = wid, j = lane;
        const float c_e = c_reg;
        const float gb0 = lds_g[b][j];
        const float gb1 = lds_g[b][HDIM + j];
        const float gb2 = lds_g[b][2 * HDIM + j];
        const float gb3 = lds_g[b][3 * HDIM + j];

        const float w00 = dWih[(0 * HDIM + j) * QDIM + 0], w01 = dWih[(0 * HDIM + j) * QDIM + 1], w02 = dWih[(0 * HDIM + j) * QDIM + 2];
        const float w10 = dWih[(1 * HDIM + j) * QDIM + 0], w11 = dWih[(1 * HDIM + j) * QDIM + 1], w12 = dWih[(1 * HDIM + j) * QDIM + 2];
        const float w20 = dWih[(2 * HDIM + j) * QDIM + 0], w21 = dWih[(2 * HDIM + j) * QDIM + 1], w22 = dWih[(2 * HDIM + j) * QDIM + 2];
        const float w30 = dWih[(3 * HDIM + j) * QDIM + 0], w31 = dWih[(3 * HDIM + j) * QDIM + 1], w32 = dWih[(3 * HDIM + j) * QDIM + 2];
        const float ow0 = oW[0 * HDIM + j], ow1 = oW[1 * HDIM + j], ow2 = oW[2 * HDIM + j];
        const float ob0 = obv[0], ob1 = obv[1], ob2 = obv[2];

        float y0 = 0.0f, y1 = 0.0f, y2 = 0.0f;
        float* outp = out + (size_t)(b0 + b) * TDEC * QDIM;

        for (int t = 0; t < TDEC; ++t) {
            float g0 = gb0 + y0 * w00 + y1 * w01 + y2 * w02;
            float g1 = gb1 + y0 * w10 + y1 * w11 + y2 * w12;
            float g2 = gb2 + y0 * w20 + y1 * w21 + y2 * w22;
            float g3 = gb3 + y0 * w30 + y1 * w31 + y2 * w32;
            float ig = sigm(g0), fg = sigm(g1), gg = tanh_f(g2), og = sigm(g3);
            float c = fg * c_e + ig * gg;
            float h = og * tanh_f(c);
            float r0 = h * ow0, r1 = h * ow1, r2 = h * ow2;
#pragma unroll
            for (int d = 1; d < 64; d <<= 1) {
                r0 += __shfl_xor(r0, d);
                r1 += __shfl_xor(r1, d);
                r2 += __shfl_xor(r2, d);
            }
            y0 = r0 + ob0;
            y1 = r1 + ob1;
            y2 = r2 + ob2;
            if (j < QDIM) outp[t * QDIM + j] = (j == 0) ? y0 : (j == 1) ? y1 : y2;
        }
    }
}

extern "C" void kernel_launch(void* const* d_in, const int* in_sizes, int n_in,
                              void* d_out, int out_size, void* d_ws, size_t ws_size,
                              hipStream_t stream) {
    (void)in_sizes; (void)n_in; (void)d_ws; (void)ws_size; (void)out_size;
    const float* x    = (const float*)d_in[0];
    const float* eWih = (const float*)d_in[1];
    const float* eWhh = (const float*)d_in[2];
    const float* ebih = (const float*)d_in[3];
    const float* ebhh = (const float*)d_in[4];
    const float* dWih = (const float*)d_in[5];
    const float* dWhh = (const float*)d_in[6];
    const float* dbih = (const float*)d_in[7];
    const float* dbhh = (const float*)d_in[8];
    const float* oW   = (const float*)d_in[9];
    const float* obv  = (const float*)d_in[10];
    float* out = (float*)d_out;

    const int B = 2048;
    dim3 grid(B / NB), block(256);
    enc_dec_kernel<<<grid, block, 0, stream>>>(x, eWih, eWhh, ebih, ebhh,
                                               dWih, dWhh, dbih, dbhh, oW, obv, out);
}

// Round 3
// 1051.011 us; speedup vs baseline: 1.0024x; 1.0024x over previous
//
#include <hip/hip_runtime.h>

#define HDIM  64
#define INDIM 7
#define QDIM  3
#define TDEC  288
#define SEQ   512
#define NB    4        // batches per block
#define CHUNK 32       // x timesteps staged per LDS chunk

__device__ __forceinline__ float fast_rcp(float x) {
    return __builtin_amdgcn_rcpf(x);   // v_rcp_f32, ~1 ulp
}
__device__ __forceinline__ float sigm(float x) {
    return fast_rcp(1.0f + __expf(-x));
}
__device__ __forceinline__ float tanh_f(float x) {
    float xx = fminf(fmaxf(x, -15.0f), 15.0f);
    float e = __expf(2.0f * xx);
    return (e - 1.0f) * fast_rcp(e + 1.0f);
}

// One block = NB batch elements, full encoder (512 steps) + decoder (288 steps).
// GEMM phase: thread (wave=gate g, lane=unit j) owns W_hh row g*64+j in VGPRs.
// amdgpu_waves_per_eu(2,2) pins the occupancy target to 2 waves/EU so the
// VGPR budget is 256 and regalloc has no pressure incentive to spill the
// pinned weights; asm pins prevent rematerialization from global.
// h read from LDS via same-address broadcast (conflict-free).
// Activation phase: thread -> (batch=wave, unit=lane), c stays in a register.
__global__ __launch_bounds__(256, 2) __attribute__((amdgpu_waves_per_eu(2, 2)))
void enc_dec_kernel(const float* __restrict__ x,
                    const float* __restrict__ eWih, const float* __restrict__ eWhh,
                    const float* __restrict__ ebih, const float* __restrict__ ebhh,
                    const float* __restrict__ dWih, const float* __restrict__ dWhh,
                    const float* __restrict__ dbih, const float* __restrict__ dbhh,
                    const float* __restrict__ oW,   const float* __restrict__ obv,
                    float* __restrict__ out)
{
    __shared__ float lds_h[NB][HDIM];
    __shared__ float lds_g[NB][4 * HDIM];
    __shared__ float lds_x[2][NB][CHUNK][8];   // padded 7->8, pad lane zeroed

    const int tid  = threadIdx.x;
    const int lane = tid & 63;
    const int wid  = tid >> 6;
    const int b0   = blockIdx.x * NB;

    const int row = wid * HDIM + lane;   // gate-matrix row this thread owns

    // ---- encoder weights into registers, PINNED (no remat possible) ----
    float4 whh[16];
#pragma unroll
    for (int m4 = 0; m4 < 16; ++m4)
        whh[m4] = *reinterpret_cast<const float4*>(&eWhh[row * HDIM + m4 * 4]);
#pragma unroll
    for (int m4 = 0; m4 < 16; ++m4)
        asm volatile("" : "+v"(whh[m4].x), "+v"(whh[m4].y), "+v"(whh[m4].z), "+v"(whh[m4].w));

    float wih[8];
#pragma unroll
    for (int k = 0; k < 7; ++k) wih[k] = eWih[row * INDIM + k];
    wih[7] = 0.0f;
#pragma unroll
    for (int k = 0; k < 7; ++k) asm volatile("" : "+v"(wih[k]));

    float bias = ebih[row] + ebhh[row];
    asm volatile("" : "+v"(bias));

    // ---- init state ----
    lds_h[wid][lane] = 0.0f;   // 256 threads cover NB*HDIM exactly
    float c_reg = 0.0f;        // c for (batch=wid, unit=lane)

    // ---- load x chunk 0 ----
    for (int i = tid; i < NB * CHUNK * 8; i += 256) {
        int b = i >> 8;          // CHUNK*8 == 256
        int r = i & 255;
        int s = r >> 3;
        int k = r & 7;
        float v = 0.0f;
        if (k < 7) v = x[((size_t)(b0 + b) * SEQ + s) * INDIM + k];
        lds_x[0][b][s][k] = v;
    }
    __syncthreads();

    // ================= encoder: 512 serial steps =================
    for (int s = 0; s < SEQ; ++s) {
        const int cs  = s & (CHUNK - 1);
        const int buf = (s >> 5) & 1;

        // ---- GEMM phase: gates[b][row] for NB batches ----
        float acc[NB];
#pragma unroll
        for (int b = 0; b < NB; ++b) acc[b] = bias;

#pragma unroll
        for (int b = 0; b < NB; ++b) {
            const float4 xlo = *reinterpret_cast<const float4*>(&lds_x[buf][b][cs][0]);
            const float4 xhi = *reinterpret_cast<const float4*>(&lds_x[buf][b][cs][4]);
            acc[b] += xlo.x * wih[0] + xlo.y * wih[1] + xlo.z * wih[2] + xlo.w * wih[3]
                    + xhi.x * wih[4] + xhi.y * wih[5] + xhi.z * wih[6];
        }
#pragma unroll
        for (int m4 = 0; m4 < 16; ++m4) {
            const float4 w = whh[m4];
            float4 hv[NB];
#pragma unroll
            for (int b = 0; b < NB; ++b)
                hv[b] = *reinterpret_cast<const float4*>(&lds_h[b][m4 * 4]);
            // component-major: dependent FMAs to the same acc are NB apart
#pragma unroll
            for (int b = 0; b < NB; ++b) acc[b] = fmaf(hv[b].x, w.x, acc[b]);
#pragma unroll
            for (int b = 0; b < NB; ++b) acc[b] = fmaf(hv[b].y, w.y, acc[b]);
#pragma unroll
            for (int b = 0; b < NB; ++b) acc[b] = fmaf(hv[b].z, w.z, acc[b]);
#pragma unroll
            for (int b = 0; b < NB; ++b) acc[b] = fmaf(hv[b].w, w.w, acc[b]);
        }
#pragma unroll
        for (int b = 0; b < NB; ++b) lds_g[b][row] = acc[b];
        __syncthreads();

        // ---- activation phase: thread -> (batch=wid, unit=lane) ----
        {
            const int b = wid, j = lane;
            float ig = sigm(lds_g[b][j]);
            float fg = sigm(lds_g[b][HDIM + j]);
            float gg = tanh_f(lds_g[b][2 * HDIM + j]);
            float og = sigm(lds_g[b][3 * HDIM + j]);
            c_reg = fg * c_reg + ig * gg;
            lds_h[b][j] = og * tanh_f(c_reg);
        }

        // ---- prefetch next x chunk (a full chunk of slack to hide HBM) ----
        if (cs == 0 && s + CHUNK < SEQ) {
            const int nbuf = buf ^ 1;
            const int s0n  = s + CHUNK;
            for (int i = tid; i < NB * CHUNK * 8; i += 256) {
                int b = i >> 8;
                int r = i & 255;
                int ss = r >> 3;
                int k = r & 7;
                float v = 0.0f;
                if (k < 7) v = x[((size_t)(b0 + b) * SEQ + (s0n + ss)) * INDIM + k];
                lds_x[nbuf][b][ss][k] = v;
            }
        }
        __syncthreads();
    }
    // lds_h = h_enc; c_reg (thread (wid,lane)) = c_enc[b][j]

    // ====== decoder gbase = b + h_enc @ dW_hh.T  (constant over all T steps) ======
    {
        float4 dwhh[16];
#pragma unroll
        for (int m4 = 0; m4 < 16; ++m4)
            dwhh[m4] = *reinterpret_cast<const float4*>(&dWhh[row * HDIM + m4 * 4]);
        const float dbias = dbih[row] + dbhh[row];

        float acc[NB];
#pragma unroll
        for (int b = 0; b < NB; ++b) acc[b] = dbias;
#pragma unroll
        for (int m4 = 0; m4 < 16; ++m4) {
            const float4 w = dwhh[m4];
            float4 hv[NB];
#pragma unroll
            for (int b = 0; b < NB; ++b)
                hv[b] = *reinterpret_cast<const float4*>(&lds_h[b][m4 * 4]);
#pragma unroll
            for (int b = 0; b < NB; ++b) acc[b] = fmaf(hv[b].x, w.x, acc[b]);
#pragma unroll
            for (int b = 0; b < NB; ++b) acc[b] = fmaf(hv[b].y, w.y, acc[b]);
#pragma unroll
            for (int b = 0; b < NB; ++b) acc[b] = fmaf(hv[b].z, w.z, acc[b]);
#pragma unroll
            for (int b = 0; b < NB; ++b) acc[b] = fmaf(hv[b].w, w.w, acc[b]);
        }
#pragma unroll
        for (int b = 0; b < NB; ++b) lds_g[b][row] = acc[b];
    }
    __syncthreads();

    // ================= decoder: wave = one batch, lane = unit =================
    {
        const int b = wid, j = lane;
        const float c_e = c_reg;
        const float gb0 = lds_g[b][j];
        const float gb1 = lds_g[b][HDIM + j];
        const float gb2 = lds_g[b][2 * HDIM + j];
        const float gb3 = lds_g[b][3 * HDIM + j];

        const float w00 = dWih[(0 * HDIM + j) * QDIM + 0], w01 = dWih[(0 * HDIM + j) * QDIM + 1], w02 = dWih[(0 * HDIM + j) * QDIM + 2];
        const float w10 = dWih[(1 * HDIM + j) * QDIM + 0], w11 = dWih[(1 * HDIM + j) * QDIM + 1], w12 = dWih[(1 * HDIM + j) * QDIM + 2];
        const float w20 = dWih[(2 * HDIM + j) * QDIM + 0], w21 = dWih[(2 * HDIM + j) * QDIM + 1], w22 = dWih[(2 * HDIM + j) * QDIM + 2];
        const float w30 = dWih[(3 * HDIM + j) * QDIM + 0], w31 = dWih[(3 * HDIM + j) * QDIM + 1], w32 = dWih[(3 * HDIM + j) * QDIM + 2];
        const float ow0 = oW[0 * HDIM + j], ow1 = oW[1 * HDIM + j], ow2 = oW[2 * HDIM + j];
        const float ob0 = obv[0], ob1 = obv[1], ob2 = obv[2];

        float y0 = 0.0f, y1 = 0.0f, y2 = 0.0f;
        float* outp = out + (size_t)(b0 + b) * TDEC * QDIM;

        for (int t = 0; t < TDEC; ++t) {
            float g0 = gb0 + y0 * w00 + y1 * w01 + y2 * w02;
            float g1 = gb1 + y0 * w10 + y1 * w11 + y2 * w12;
            float g2 = gb2 + y0 * w20 + y1 * w21 + y2 * w22;
            float g3 = gb3 + y0 * w30 + y1 * w31 + y2 * w32;
            float ig = sigm(g0), fg = sigm(g1), gg = tanh_f(g2), og = sigm(g3);
            float c = fg * c_e + ig * gg;
            float h = og * tanh_f(c);
            float r0 = h * ow0, r1 = h * ow1, r2 = h * ow2;
#pragma unroll
            for (int d = 1; d < 64; d <<= 1) {
                r0 += __shfl_xor(r0, d);
                r1 += __shfl_xor(r1, d);
                r2 += __shfl_xor(r2, d);
            }
            y0 = r0 + ob0;
            y1 = r1 + ob1;
            y2 = r2 + ob2;
            if (j < QDIM) outp[t * QDIM + j] = (j == 0) ? y0 : (j == 1) ? y1 : y2;
        }
    }
}

extern "C" void kernel_launch(void* const* d_in, const int* in_sizes, int n_in,
                              void* d_out, int out_size, void* d_ws, size_t ws_size,
                              hipStream_t stream) {
    (void)in_sizes; (void)n_in; (void)d_ws; (void)ws_size; (void)out_size;
    const float* x    = (const float*)d_in[0];
    const float* eWih = (const float*)d_in[1];
    const float* eWhh = (const float*)d_in[2];
    const float* ebih = (const float*)d_in[3];
    const float* ebhh = (const float*)d_in[4];
    const float* dWih = (const float*)d_in[5];
    const float* dWhh = (const float*)d_in[6];
    const float* dbih = (const float*)d_in[7];
    const float* dbhh = (const float*)d_in[8];
    const float* oW   = (const float*)d_in[9];
    const float* obv  = (const float*)d_in[10];
    float* out = (float*)d_out;

    const int B = 2048;
    dim3 grid(B / NB), block(256);
    enc_dec_kernel<<<grid, block, 0, stream>>>(x, eWih, eWhh, ebih, ebhh,
                                               dWih, dWhh, dbih, dbhh, oW, obv, out);
}

// Round 4
// 741.511 us; speedup vs baseline: 1.4208x; 1.4174x over previous
//
#include <hip/hip_runtime.h>

#define HDIM  64
#define INDIM 7
#define QDIM  3
#define TDEC  288
#define SEQ   512
#define NB    4        // batches per block
#define CHUNK 32       // x timesteps staged per LDS chunk
#define HPAD  68       // lds_h row stride: (4b+8g+j)%32 -> <=2-way bank aliasing (free)
#define GPAD  264      // lds_g row stride: (8b+row)%32 -> <=2-way

typedef __attribute__((ext_vector_type(8))) short bf16x8;   // 8 bf16 in 4 VGPRs
typedef __attribute__((ext_vector_type(4))) float f32x4;

__device__ __forceinline__ float fast_rcp(float x) { return __builtin_amdgcn_rcpf(x); }
__device__ __forceinline__ float sigm(float x) { return fast_rcp(1.0f + __expf(-x)); }
__device__ __forceinline__ float tanh_f(float x) {
    float xx = fminf(fmaxf(x, -15.0f), 15.0f);
    float e = __expf(2.0f * xx);
    return (e - 1.0f) * fast_rcp(e + 1.0f);
}
// round-to-nearest-even fp32 -> bf16 bits
__device__ __forceinline__ short f2bf(float f) {
    union { float f; unsigned u; } v; v.f = f;
    unsigned r = (v.u + 0x7fffu + ((v.u >> 16) & 1u)) >> 16;
    return (short)r;
}
__device__ __forceinline__ float bf2f(short s) {
    union { unsigned u; float f; } v; v.u = ((unsigned)(unsigned short)s) << 16;
    return v.f;
}

// One block = 4 batches, full encoder + decoder.
// Encoder h@Whh.T via MFMA 16x16x32 bf16 hi/lo (3-pass ~fp32 precision):
//   wave g owns gate g (rows 64g..64g+63 = 4 M-tiles); A-frags (Whh hi/lo)
//   preloaded; B-frags (h hi/lo) rebuilt from lds_h each step (4 b128 reads).
//   A and B use the SAME k-placement (lane>>4)*8+e, so the contraction is
//   correct for any HW k-layout (A/B layouts are mutual transposes).
//   C/D: col(batch)=lane&15, row=(lane>>4)*4+reg  [HW-verified m89/m91].
// x@Wih + bias + activations stay pure fp32 in the activation phase.
__global__ __launch_bounds__(256, 2)
void enc_dec_kernel(const float* __restrict__ x,
                    const float* __restrict__ eWih, const float* __restrict__ eWhh,
                    const float* __restrict__ ebih, const float* __restrict__ ebhh,
                    const float* __restrict__ dWih, const float* __restrict__ dWhh,
                    const float* __restrict__ dbih, const float* __restrict__ dbhh,
                    const float* __restrict__ oW,   const float* __restrict__ obv,
                    float* __restrict__ out)
{
    __shared__ __align__(16) float lds_h[NB][HPAD];
    __shared__ __align__(16) float lds_g[NB][GPAD];
    __shared__ __align__(16) float lds_x[2][NB][CHUNK][8];   // padded 7->8, pad zeroed

    const int tid  = threadIdx.x;
    const int lane = tid & 63;
    const int wid  = tid >> 6;
    const int b0   = blockIdx.x * NB;
    const int row  = wid * HDIM + lane;     // used by decoder-gbase phase

    // ---- MFMA A-fragments: Whh rows of gate `wid`, hi/lo bf16 ----
    bf16x8 a_hi[4][2], a_lo[4][2];
    {
        const int m = lane & 15, g16 = lane >> 4;
#pragma unroll
        for (int Mt = 0; Mt < 4; ++Mt) {
#pragma unroll
            for (int kt = 0; kt < 2; ++kt) {
                const float* p = eWhh + (size_t)(wid * 64 + Mt * 16 + m) * HDIM + kt * 32 + g16 * 8;
                f32x4 v0 = *(const f32x4*)p;
                f32x4 v1 = *(const f32x4*)(p + 4);
#pragma unroll
                for (int e = 0; e < 4; ++e) {
                    short hi = f2bf(v0[e]);
                    a_hi[Mt][kt][e] = hi;
                    a_lo[Mt][kt][e] = f2bf(v0[e] - bf2f(hi));
                }
#pragma unroll
                for (int e = 0; e < 4; ++e) {
                    short hi = f2bf(v1[e]);
                    a_hi[Mt][kt][4 + e] = hi;
                    a_lo[Mt][kt][4 + e] = f2bf(v1[e] - bf2f(hi));
                }
            }
        }
    }

    // ---- per-thread fp32 constants for the activation phase (b=wid, j=lane) ----
    float wih_r[4][7];
    float bias_r[4];
#pragma unroll
    for (int g = 0; g < 4; ++g) {
        const int r = g * HDIM + lane;
#pragma unroll
        for (int k = 0; k < 7; ++k) wih_r[g][k] = eWih[r * INDIM + k];
        bias_r[g] = ebih[r] + ebhh[r];
    }

    // ---- init state ----
    lds_h[wid][lane] = 0.0f;   // cols 0..63 of each row; pad never read by B-build
    float c_reg = 0.0f;        // c for (batch=wid, unit=lane)

    // ---- load x chunk 0 ----
    for (int i = tid; i < NB * CHUNK * 8; i += 256) {
        int b = i >> 8;          // CHUNK*8 == 256
        int r = i & 255;
        int s = r >> 3;
        int k = r & 7;
        float v = 0.0f;
        if (k < 7) v = x[((size_t)(b0 + b) * SEQ + s) * INDIM + k];
        lds_x[0][b][s][k] = v;
    }
    __syncthreads();

    // ================= encoder: 512 serial steps =================
    for (int s = 0; s < SEQ; ++s) {
        const int cs  = s & (CHUNK - 1);
        const int buf = (s >> 5) & 1;

        // ---- build B fragments (h hi/lo), same k-placement as A ----
        bf16x8 bhi[2], blo[2];
        {
            const int bb = lane & 3, g16 = lane >> 4;   // col n -> batch n&3 (cols 4..15 replicate)
#pragma unroll
            for (int kt = 0; kt < 2; ++kt) {
                const float* hp = &lds_h[bb][kt * 32 + g16 * 8];
                f32x4 h0 = *(const f32x4*)hp;
                f32x4 h1 = *(const f32x4*)(hp + 4);
#pragma unroll
                for (int e = 0; e < 4; ++e) {
                    short hi = f2bf(h0[e]);
                    bhi[kt][e] = hi;
                    blo[kt][e] = f2bf(h0[e] - bf2f(hi));
                }
#pragma unroll
                for (int e = 0; e < 4; ++e) {
                    short hi = f2bf(h1[e]);
                    bhi[kt][4 + e] = hi;
                    blo[kt][4 + e] = f2bf(h1[e] - bf2f(hi));
                }
            }
        }

        // ---- MFMA: 3-pass hi/lo, interleaved across M-tiles (dep distance 4) ----
        f32x4 acc[4] = {{0,0,0,0},{0,0,0,0},{0,0,0,0},{0,0,0,0}};
#pragma unroll
        for (int kt = 0; kt < 2; ++kt) {
#pragma unroll
            for (int Mt = 0; Mt < 4; ++Mt)
                acc[Mt] = __builtin_amdgcn_mfma_f32_16x16x32_bf16(a_hi[Mt][kt], bhi[kt], acc[Mt], 0, 0, 0);
#pragma unroll
            for (int Mt = 0; Mt < 4; ++Mt)
                acc[Mt] = __builtin_amdgcn_mfma_f32_16x16x32_bf16(a_lo[Mt][kt], bhi[kt], acc[Mt], 0, 0, 0);
#pragma unroll
            for (int Mt = 0; Mt < 4; ++Mt)
                acc[Mt] = __builtin_amdgcn_mfma_f32_16x16x32_bf16(a_hi[Mt][kt], blo[kt], acc[Mt], 0, 0, 0);
        }

        // ---- write D: lanes with col<4 hold valid batches; rows r contiguous -> b128 ----
        if ((lane & 12) == 0) {
            const int bb = lane & 3, g16 = lane >> 4;
#pragma unroll
            for (int Mt = 0; Mt < 4; ++Mt)
                *(f32x4*)&lds_g[bb][wid * 64 + Mt * 16 + g16 * 4] = acc[Mt];
        }
        __syncthreads();

        // ---- activation phase (fp32): thread -> (batch=wid, unit=lane) ----
        {
            const int b = wid, j = lane;
            f32x4 x0 = *(const f32x4*)&lds_x[buf][b][cs][0];
            f32x4 x1 = *(const f32x4*)&lds_x[buf][b][cs][4];
            float pre[4];
#pragma unroll
            for (int g = 0; g < 4; ++g) {
                float p = lds_g[b][g * 64 + j] + bias_r[g];
                p += x0[0] * wih_r[g][0] + x0[1] * wih_r[g][1] + x0[2] * wih_r[g][2]
                   + x0[3] * wih_r[g][3] + x1[0] * wih_r[g][4] + x1[1] * wih_r[g][5]
                   + x1[2] * wih_r[g][6];
                pre[g] = p;
            }
            float ig = sigm(pre[0]), fg = sigm(pre[1]), gg = tanh_f(pre[2]), og = sigm(pre[3]);
            c_reg = fg * c_reg + ig * gg;
            lds_h[b][j] = og * tanh_f(c_reg);
        }

        // ---- prefetch next x chunk ----
        if (cs == 0 && s + CHUNK < SEQ) {
            const int nbuf = buf ^ 1;
            const int s0n  = s + CHUNK;
            for (int i = tid; i < NB * CHUNK * 8; i += 256) {
                int b = i >> 8;
                int r = i & 255;
                int ss = r >> 3;
                int k = r & 7;
                float v = 0.0f;
                if (k < 7) v = x[((size_t)(b0 + b) * SEQ + (s0n + ss)) * INDIM + k];
                lds_x[nbuf][b][ss][k] = v;
            }
        }
        __syncthreads();
    }
    // lds_h = h_enc; c_reg (thread (wid,lane)) = c_enc[b][j]

    // ====== decoder gbase = b + h_enc @ dW_hh.T (fp32, one-time) ======
    {
        float4 dwhh[16];
#pragma unroll
        for (int m4 = 0; m4 < 16; ++m4)
            dwhh[m4] = *reinterpret_cast<const float4*>(&dWhh[row * HDIM + m4 * 4]);
        const float dbias = dbih[row] + dbhh[row];

        float acc[NB];
#pragma unroll
        for (int b = 0; b < NB; ++b) acc[b] = dbias;
#pragma unroll
        for (int m4 = 0; m4 < 16; ++m4) {
            const float4 w = dwhh[m4];
            float4 hv[NB];
#pragma unroll
            for (int b = 0; b < NB; ++b)
                hv[b] = *reinterpret_cast<const float4*>(&lds_h[b][m4 * 4]);
#pragma unroll
            for (int b = 0; b < NB; ++b) acc[b] = fmaf(hv[b].x, w.x, acc[b]);
#pragma unroll
            for (int b = 0; b < NB; ++b) acc[b] = fmaf(hv[b].y, w.y, acc[b]);
#pragma unroll
            for (int b = 0; b < NB; ++b) acc[b] = fmaf(hv[b].z, w.z, acc[b]);
#pragma unroll
            for (int b = 0; b < NB; ++b) acc[b] = fmaf(hv[b].w, w.w, acc[b]);
        }
#pragma unroll
        for (int b = 0; b < NB; ++b) lds_g[b][row] = acc[b];
    }
    __syncthreads();

    // ================= decoder: wave = one batch, lane = unit =================
    {
        const int b = wid, j = lane;
        const float c_e = c_reg;
        const float gb0 = lds_g[b][j];
        const float gb1 = lds_g[b][HDIM + j];
        const float gb2 = lds_g[b][2 * HDIM + j];
        const float gb3 = lds_g[b][3 * HDIM + j];

        const float w00 = dWih[(0 * HDIM + j) * QDIM + 0], w01 = dWih[(0 * HDIM + j) * QDIM + 1], w02 = dWih[(0 * HDIM + j) * QDIM + 2];
        const float w10 = dWih[(1 * HDIM + j) * QDIM + 0], w11 = dWih[(1 * HDIM + j) * QDIM + 1], w12 = dWih[(1 * HDIM + j) * QDIM + 2];
        const float w20 = dWih[(2 * HDIM + j) * QDIM + 0], w21 = dWih[(2 * HDIM + j) * QDIM + 1], w22 = dWih[(2 * HDIM + j) * QDIM + 2];
        const float w30 = dWih[(3 * HDIM + j) * QDIM + 0], w31 = dWih[(3 * HDIM + j) * QDIM + 1], w32 = dWih[(3 * HDIM + j) * QDIM + 2];
        const float ow0 = oW[0 * HDIM + j], ow1 = oW[1 * HDIM + j], ow2 = oW[2 * HDIM + j];
        const float ob0 = obv[0], ob1 = obv[1], ob2 = obv[2];

        float y0 = 0.0f, y1 = 0.0f, y2 = 0.0f;
        float* outp = out + (size_t)(b0 + b) * TDEC * QDIM;

        for (int t = 0; t < TDEC; ++t) {
            float g0 = gb0 + y0 * w00 + y1 * w01 + y2 * w02;
            float g1 = gb1 + y0 * w10 + y1 * w11 + y2 * w12;
            float g2 = gb2 + y0 * w20 + y1 * w21 + y2 * w22;
            float g3 = gb3 + y0 * w30 + y1 * w31 + y2 * w32;
            float ig = sigm(g0), fg = sigm(g1), gg = tanh_f(g2), og = sigm(g3);
            float c = fg * c_e + ig * gg;
            float h = og * tanh_f(c);
            float r0 = h * ow0, r1 = h * ow1, r2 = h * ow2;
#pragma unroll
            for (int d = 1; d < 64; d <<= 1) {
                r0 += __shfl_xor(r0, d);
                r1 += __shfl_xor(r1, d);
                r2 += __shfl_xor(r2, d);
            }
            y0 = r0 + ob0;
            y1 = r1 + ob1;
            y2 = r2 + ob2;
            if (j < QDIM) outp[t * QDIM + j] = (j == 0) ? y0 : (j == 1) ? y1 : y2;
        }
    }
}

extern "C" void kernel_launch(void* const* d_in, const int* in_sizes, int n_in,
                              void* d_out, int out_size, void* d_ws, size_t ws_size,
                              hipStream_t stream) {
    (void)in_sizes; (void)n_in; (void)d_ws; (void)ws_size; (void)out_size;
    const float* x    = (const float*)d_in[0];
    const float* eWih = (const float*)d_in[1];
    const float* eWhh = (const float*)d_in[2];
    const float* ebih = (const float*)d_in[3];
    const float* ebhh = (const float*)d_in[4];
    const float* dWih = (const float*)d_in[5];
    const float* dWhh = (const float*)d_in[6];
    const float* dbih = (const float*)d_in[7];
    const float* dbhh = (const float*)d_in[8];
    const float* oW   = (const float*)d_in[9];
    const float* obv  = (const float*)d_in[10];
    float* out = (float*)d_out;

    const int B = 2048;
    dim3 grid(B / NB), block(256);
    enc_dec_kernel<<<grid, block, 0, stream>>>(x, eWih, eWhh, ebih, ebhh,
                                               dWih, dWhh, dbih, dbhh, oW, obv, out);
}

// Round 5
// 588.402 us; speedup vs baseline: 1.7905x; 1.2602x over previous
//
#include <hip/hip_runtime.h>

#define HDIM  64
#define INDIM 7
#define QDIM  3
#define TDEC  288
#define SEQ   512
#define NB    4        // batches per block
#define CHUNK 32       // x timesteps staged per LDS chunk
#define HPAD  68       // fp32 h row stride (decoder use only)
#define GPAD  264      // lds_g row stride: <=2-way bank aliasing
#define HBST  80       // bf16 h row stride in shorts (160B) -> <=2-way

typedef __attribute__((ext_vector_type(8))) short bf16x8;   // 8 bf16 in 4 VGPRs
typedef __attribute__((ext_vector_type(4))) float f32x4;

__device__ __forceinline__ float fast_rcp(float x) { return __builtin_amdgcn_rcpf(x); }
__device__ __forceinline__ float sigm(float x) { return fast_rcp(1.0f + __expf(-x)); }
__device__ __forceinline__ float tanh_f(float x) {
    float xx = fminf(fmaxf(x, -15.0f), 15.0f);
    float e = __expf(2.0f * xx);
    return (e - 1.0f) * fast_rcp(e + 1.0f);
}
// round-to-nearest-even fp32 -> bf16 bits
__device__ __forceinline__ short f2bf(float f) {
    union { float f; unsigned u; } v; v.f = f;
    unsigned r = (v.u + 0x7fffu + ((v.u >> 16) & 1u)) >> 16;
    return (short)r;
}
__device__ __forceinline__ float bf2f(short s) {
    union { unsigned u; float f; } v; v.u = ((unsigned)(unsigned short)s) << 16;
    return v.f;
}

// One block = 4 batches, full encoder + decoder.
// Encoder h@Whh.T via MFMA 16x16x32 bf16 hi/lo (3-pass ~fp32 precision).
// KEY CHANGE vs R4: h is stored in LDS as packed bf16 hi/lo (converted ONCE
// by the producer thread in the activation phase); the per-wave B-fragment
// build is now 4 pure ds_read_b128 — no per-step fp32->bf16 VALU, no 4x
// cross-wave redundancy.
__global__ __launch_bounds__(256, 2)
void enc_dec_kernel(const float* __restrict__ x,
                    const float* __restrict__ eWih, const float* __restrict__ eWhh,
                    const float* __restrict__ ebih, const float* __restrict__ ebhh,
                    const float* __restrict__ dWih, const float* __restrict__ dWhh,
                    const float* __restrict__ dbih, const float* __restrict__ dbhh,
                    const float* __restrict__ oW,   const float* __restrict__ obv,
                    float* __restrict__ out)
{
    __shared__ __align__(16) short lds_hhi[NB][HBST];   // h hi bf16, cols 0..63 used
    __shared__ __align__(16) short lds_hlo[NB][HBST];   // h lo bf16
    __shared__ __align__(16) float lds_hf[NB][HPAD];    // fp32 h_enc (final step only)
    __shared__ __align__(16) float lds_g[NB][GPAD];
    __shared__ __align__(16) float lds_x[2][NB][CHUNK][8];   // padded 7->8, pad zeroed

    const int tid  = threadIdx.x;
    const int lane = tid & 63;
    const int wid  = tid >> 6;
    const int b0   = blockIdx.x * NB;
    const int row  = wid * HDIM + lane;     // used by decoder-gbase phase

    // ---- MFMA A-fragments: Whh rows of gate `wid`, hi/lo bf16 ----
    bf16x8 a_hi[4][2], a_lo[4][2];
    {
        const int m = lane & 15, g16 = lane >> 4;
#pragma unroll
        for (int Mt = 0; Mt < 4; ++Mt) {
#pragma unroll
            for (int kt = 0; kt < 2; ++kt) {
                const float* p = eWhh + (size_t)(wid * 64 + Mt * 16 + m) * HDIM + kt * 32 + g16 * 8;
                f32x4 v0 = *(const f32x4*)p;
                f32x4 v1 = *(const f32x4*)(p + 4);
#pragma unroll
                for (int e = 0; e < 4; ++e) {
                    short hi = f2bf(v0[e]);
                    a_hi[Mt][kt][e] = hi;
                    a_lo[Mt][kt][e] = f2bf(v0[e] - bf2f(hi));
                }
#pragma unroll
                for (int e = 0; e < 4; ++e) {
                    short hi = f2bf(v1[e]);
                    a_hi[Mt][kt][4 + e] = hi;
                    a_lo[Mt][kt][4 + e] = f2bf(v1[e] - bf2f(hi));
                }
            }
        }
    }

    // ---- per-thread fp32 constants for the activation phase (b=wid, j=lane) ----
    float wih_r[4][7];
    float bias_r[4];
#pragma unroll
    for (int g = 0; g < 4; ++g) {
        const int r = g * HDIM + lane;
#pragma unroll
        for (int k = 0; k < 7; ++k) wih_r[g][k] = eWih[r * INDIM + k];
        bias_r[g] = ebih[r] + ebhh[r];
    }

    // ---- init state: h = 0 ----
    lds_hhi[wid][lane] = 0;
    lds_hlo[wid][lane] = 0;
    float c_reg = 0.0f;        // c for (batch=wid, unit=lane)

    // ---- load x chunk 0 ----
    for (int i = tid; i < NB * CHUNK * 8; i += 256) {
        int b = i >> 8;          // CHUNK*8 == 256
        int r = i & 255;
        int s = r >> 3;
        int k = r & 7;
        float v = 0.0f;
        if (k < 7) v = x[((size_t)(b0 + b) * SEQ + s) * INDIM + k];
        lds_x[0][b][s][k] = v;
    }
    __syncthreads();

    // ================= encoder: 512 serial steps =================
    for (int s = 0; s < SEQ; ++s) {
        const int cs  = s & (CHUNK - 1);
        const int buf = (s >> 5) & 1;

        // ---- B fragments: pure b128 reads of pre-split bf16 h ----
        bf16x8 bhi[2], blo[2];
        {
            const int bb = lane & 3, g16 = lane >> 4;   // col n -> batch n&3 (cols 4..15 replicate)
#pragma unroll
            for (int kt = 0; kt < 2; ++kt) {
                bhi[kt] = *(const bf16x8*)&lds_hhi[bb][kt * 32 + g16 * 8];
                blo[kt] = *(const bf16x8*)&lds_hlo[bb][kt * 32 + g16 * 8];
            }
        }

        // ---- MFMA: 3-pass hi/lo, interleaved across M-tiles (dep distance 4) ----
        f32x4 acc[4] = {{0,0,0,0},{0,0,0,0},{0,0,0,0},{0,0,0,0}};
#pragma unroll
        for (int kt = 0; kt < 2; ++kt) {
#pragma unroll
            for (int Mt = 0; Mt < 4; ++Mt)
                acc[Mt] = __builtin_amdgcn_mfma_f32_16x16x32_bf16(a_hi[Mt][kt], bhi[kt], acc[Mt], 0, 0, 0);
#pragma unroll
            for (int Mt = 0; Mt < 4; ++Mt)
                acc[Mt] = __builtin_amdgcn_mfma_f32_16x16x32_bf16(a_lo[Mt][kt], bhi[kt], acc[Mt], 0, 0, 0);
#pragma unroll
            for (int Mt = 0; Mt < 4; ++Mt)
                acc[Mt] = __builtin_amdgcn_mfma_f32_16x16x32_bf16(a_hi[Mt][kt], blo[kt], acc[Mt], 0, 0, 0);
        }

        // ---- write D: lanes with col<4 hold valid batches; rows contiguous -> b128 ----
        if ((lane & 12) == 0) {
            const int bb = lane & 3, g16 = lane >> 4;
#pragma unroll
            for (int Mt = 0; Mt < 4; ++Mt)
                *(f32x4*)&lds_g[bb][wid * 64 + Mt * 16 + g16 * 4] = acc[Mt];
        }
        __syncthreads();

        // ---- activation phase (fp32): thread -> (batch=wid, unit=lane) ----
        {
            const int b = wid, j = lane;
            f32x4 x0 = *(const f32x4*)&lds_x[buf][b][cs][0];
            f32x4 x1 = *(const f32x4*)&lds_x[buf][b][cs][4];
            float pre[4];
#pragma unroll
            for (int g = 0; g < 4; ++g) {
                float p = lds_g[b][g * 64 + j] + bias_r[g];
                p += x0[0] * wih_r[g][0] + x0[1] * wih_r[g][1] + x0[2] * wih_r[g][2]
                   + x0[3] * wih_r[g][3] + x1[0] * wih_r[g][4] + x1[1] * wih_r[g][5]
                   + x1[2] * wih_r[g][6];
                pre[g] = p;
            }
            float ig = sigm(pre[0]), fg = sigm(pre[1]), gg = tanh_f(pre[2]), og = sigm(pre[3]);
            c_reg = fg * c_reg + ig * gg;
            float h = og * tanh_f(c_reg);
            short hi = f2bf(h);
            lds_hhi[b][j] = hi;
            lds_hlo[b][j] = f2bf(h - bf2f(hi));
            if (s + 1 == SEQ) lds_hf[b][j] = h;   // fp32 h_enc for decoder gbase
        }

        // ---- prefetch next x chunk ----
        if (cs == 0 && s + CHUNK < SEQ) {
            const int nbuf = buf ^ 1;
            const int s0n  = s + CHUNK;
            for (int i = tid; i < NB * CHUNK * 8; i += 256) {
                int b = i >> 8;
                int r = i & 255;
                int ss = r >> 3;
                int k = r & 7;
                float v = 0.0f;
                if (k < 7) v = x[((size_t)(b0 + b) * SEQ + (s0n + ss)) * INDIM + k];
                lds_x[nbuf][b][ss][k] = v;
            }
        }
        __syncthreads();
    }
    // lds_hf = h_enc; c_reg (thread (wid,lane)) = c_enc[b][j]

    // ====== decoder gbase = b + h_enc @ dW_hh.T (fp32, one-time) ======
    {
        float4 dwhh[16];
#pragma unroll
        for (int m4 = 0; m4 < 16; ++m4)
            dwhh[m4] = *reinterpret_cast<const float4*>(&dWhh[row * HDIM + m4 * 4]);
        const float dbias = dbih[row] + dbhh[row];

        float acc[NB];
#pragma unroll
        for (int b = 0; b < NB; ++b) acc[b] = dbias;
#pragma unroll
        for (int m4 = 0; m4 < 16; ++m4) {
            const float4 w = dwhh[m4];
            float4 hv[NB];
#pragma unroll
            for (int b = 0; b < NB; ++b)
                hv[b] = *reinterpret_cast<const float4*>(&lds_hf[b][m4 * 4]);
#pragma unroll
            for (int b = 0; b < NB; ++b) acc[b] = fmaf(hv[b].x, w.x, acc[b]);
#pragma unroll
            for (int b = 0; b < NB; ++b) acc[b] = fmaf(hv[b].y, w.y, acc[b]);
#pragma unroll
            for (int b = 0; b < NB; ++b) acc[b] = fmaf(hv[b].z, w.z, acc[b]);
#pragma unroll
            for (int b = 0; b < NB; ++b) acc[b] = fmaf(hv[b].w, w.w, acc[b]);
        }
#pragma unroll
        for (int b = 0; b < NB; ++b) lds_g[b][row] = acc[b];
    }
    __syncthreads();

    // ================= decoder: wave = one batch, lane = unit =================
    {
        const int b = wid, j = lane;
        const float c_e = c_reg;
        const float gb0 = lds_g[b][j];
        const float gb1 = lds_g[b][HDIM + j];
        const float gb2 = lds_g[b][2 * HDIM + j];
        const float gb3 = lds_g[b][3 * HDIM + j];

        const float w00 = dWih[(0 * HDIM + j) * QDIM + 0], w01 = dWih[(0 * HDIM + j) * QDIM + 1], w02 = dWih[(0 * HDIM + j) * QDIM + 2];
        const float w10 = dWih[(1 * HDIM + j) * QDIM + 0], w11 = dWih[(1 * HDIM + j) * QDIM + 1], w12 = dWih[(1 * HDIM + j) * QDIM + 2];
        const float w20 = dWih[(2 * HDIM + j) * QDIM + 0], w21 = dWih[(2 * HDIM + j) * QDIM + 1], w22 = dWih[(2 * HDIM + j) * QDIM + 2];
        const float w30 = dWih[(3 * HDIM + j) * QDIM + 0], w31 = dWih[(3 * HDIM + j) * QDIM + 1], w32 = dWih[(3 * HDIM + j) * QDIM + 2];
        const float ow0 = oW[0 * HDIM + j], ow1 = oW[1 * HDIM + j], ow2 = oW[2 * HDIM + j];
        const float ob0 = obv[0], ob1 = obv[1], ob2 = obv[2];

        float y0 = 0.0f, y1 = 0.0f, y2 = 0.0f;
        float* outp = out + (size_t)(b0 + b) * TDEC * QDIM;

        for (int t = 0; t < TDEC; ++t) {
            float g0 = gb0 + y0 * w00 + y1 * w01 + y2 * w02;
            float g1 = gb1 + y0 * w10 + y1 * w11 + y2 * w12;
            float g2 = gb2 + y0 * w20 + y1 * w21 + y2 * w22;
            float g3 = gb3 + y0 * w30 + y1 * w31 + y2 * w32;
            float ig = sigm(g0), fg = sigm(g1), gg = tanh_f(g2), og = sigm(g3);
            float c = fg * c_e + ig * gg;
            float h = og * tanh_f(c);
            float r0 = h * ow0, r1 = h * ow1, r2 = h * ow2;
#pragma unroll
            for (int d = 1; d < 64; d <<= 1) {
                r0 += __shfl_xor(r0, d);
                r1 += __shfl_xor(r1, d);
                r2 += __shfl_xor(r2, d);
            }
            y0 = r0 + ob0;
            y1 = r1 + ob1;
            y2 = r2 + ob2;
            if (j < QDIM) outp[t * QDIM + j] = (j == 0) ? y0 : (j == 1) ? y1 : y2;
        }
    }
}

extern "C" void kernel_launch(void* const* d_in, const int* in_sizes, int n_in,
                              void* d_out, int out_size, void* d_ws, size_t ws_size,
                              hipStream_t stream) {
    (void)in_sizes; (void)n_in; (void)d_ws; (void)ws_size; (void)out_size;
    const float* x    = (const float*)d_in[0];
    const float* eWih = (const float*)d_in[1];
    const float* eWhh = (const float*)d_in[2];
    const float* ebih = (const float*)d_in[3];
    const float* ebhh = (const float*)d_in[4];
    const float* dWih = (const float*)d_in[5];
    const float* dWhh = (const float*)d_in[6];
    const float* dbih = (const float*)d_in[7];
    const float* dbhh = (const float*)d_in[8];
    const float* oW   = (const float*)d_in[9];
    const float* obv  = (const float*)d_in[10];
    float* out = (float*)d_out;

    const int B = 2048;
    dim3 grid(B / NB), block(256);
    enc_dec_kernel<<<grid, block, 0, stream>>>(x, eWih, eWhh, ebih, ebhh,
                                               dWih, dWhh, dbih, dbhh, oW, obv, out);
}